// Round 8
// baseline (198.458 us; speedup 1.0000x reference)
//
#include <hip/hip_runtime.h>
#include <hip/hip_bf16.h>

#define BATCH   16384
#define NSTEPS  100
#define DT_     0.01f
#define SQRTDT  0.1f
#define SIGMA0_ 0.5f

typedef short     bf16x8 __attribute__((ext_vector_type(8)));
typedef _Float16  f16x4  __attribute__((ext_vector_type(4)));
typedef float     f32x4  __attribute__((ext_vector_type(4)));

__global__ void zero_out_kernel(float* out) { if (threadIdx.x == 0) out[0] = 0.0f; }

static __device__ __forceinline__ unsigned packbf16(float a, float b) {
    union { __hip_bfloat162 h; unsigned u; } cv;
    cv.h = __float22bfloat162_rn(make_float2(a, b));
    return cv.u;
}
static __device__ __forceinline__ unsigned short bf16bits(float x) {
    union { __hip_bfloat16 h; unsigned short u; } cv;
    cv.h = __float2bfloat16(x);
    return cv.u;
}

// One wave = 16 paths, BOTH MLPs, no LDS, no barriers. 1024 waves total
// (256 blocks x 256 thr, 4 free-running waves each) = 1 wave/SIMD; register
// budget up to 512 VGPR makes everything loop-resident. Layer-2: 16 MFMAs
// (W2^T resident A-frags). Layer-3: 8 chained 16x16x16 f16 MFMAs into ONE
// stacked P (rows 0-2 = z, row 3 = q via zero-padded A3 rows); epilogue gets
// (z,q) by 4 lane-shuffles from the q4==0 lanes. Noise pipelined 2 steps.
__launch_bounds__(256, 1)
__global__ void deepbsde_kernel(
    const float* __restrict__ y0,  const float* __restrict__ Y0,
    const float* __restrict__ zW1, const float* __restrict__ zb1,
    const float* __restrict__ zW2, const float* __restrict__ zb2,
    const float* __restrict__ zW3, const float* __restrict__ zb3,
    const float* __restrict__ qW1, const float* __restrict__ qb1,
    const float* __restrict__ qW2, const float* __restrict__ qb2,
    const float* __restrict__ qW3, const float* __restrict__ qb3,
    const float* __restrict__ dW,  const float* __restrict__ dZ,
    float* __restrict__ out)
{
    const int tid  = threadIdx.x;
    const int lane = tid & 63;
    const int w    = tid >> 6;
    const int ln15 = lane & 15, q4 = lane >> 4;
    const int gw   = (blockIdx.x << 2) + w;      // global wave id, 0..1023
    const int pl   = (gw << 4) + ln15;           // this lane's path (x4 replicas)

    // layer-1 consts at this lane's frag k indices: k = 32f + 8q4 + j
    float A1z[16], B1z[16], C1z[16], A1q[16], B1q[16], C1q[16];
#pragma unroll
    for (int f = 0; f < 2; ++f)
#pragma unroll
        for (int j = 0; j < 8; ++j) {
            int k = 32*f + 8*q4 + j, idx = f*8 + j;
            A1z[idx] = zW1[k]; B1z[idx] = zW1[64 + k]; C1z[idx] = zb1[k];
            A1q[idx] = qW1[k]; B1q[idx] = qW1[64 + k]; C1q[idx] = qb1[k];
        }

    // resident W2^T A-frags (layout verified R5-R7): A[n=16tN+ln15][k=32f+8q4+j]
    bf16x8 AfZ[4][2], AfQ[4][2];
#pragma unroll
    for (int tN = 0; tN < 4; ++tN)
#pragma unroll
        for (int f = 0; f < 2; ++f)
#pragma unroll
            for (int j = 0; j < 8; ++j) {
                int k = 32*f + 8*q4 + j, n = 16*tN + ln15;
                AfZ[tN][f][j] = (short)bf16bits(zW2[k*64 + n]);
                AfQ[tN][f][j] = (short)bf16bits(qW2[k*64 + n]);
            }

    // layer-2 bias along Dt rows: row n = 16tN + 4q4 + r
    f32x4 b2zv[4], b2qv[4];
#pragma unroll
    for (int tN = 0; tN < 4; ++tN)
#pragma unroll
        for (int r = 0; r < 4; ++r) {
            b2zv[tN][r] = zb2[16*tN + 4*q4 + r];
            b2qv[tN][r] = qb2[16*tN + 4*q4 + r];
        }

    // stacked W3^T A-frags (16x16x16): A[m=ln15][k=16tN+4q4+j]
    // z-chain rows 0-2 = zW3 cols, row 3 = 0; q-chain row 3 = qW3, rows 0-2 = 0
    f16x4 A3z[4], A3q[4];
#pragma unroll
    for (int tN = 0; tN < 4; ++tN) {
#pragma unroll
        for (int j = 0; j < 4; ++j) {
            int n = 16*tN + 4*q4 + j;
            float vz = (ln15 < 3)  ? zW3[n*3 + ln15] : 0.0f;
            float vq = (ln15 == 3) ? qW3[n]          : 0.0f;
            A3z[tN][j] = (_Float16)vz;
            A3q[tN][j] = (_Float16)vq;
        }
    }

    float y = y0[0], Yv = Y0[0], t = 0.0f, acc = 0.0f;
    const float zb30 = zb3[0], zb31 = zb3[1], zb32 = zb3[2], qb30 = qb3[0];

    const size_t STRIDE = (size_t)BATCH * 3;
    const float* pW = dW + (size_t)pl * 3;
    const float* pZ = dZ + (size_t)pl * 3;
    // 2-deep noise pipeline
    float wa0 = pW[0], wa1 = pW[1], wa2 = pW[2];
    float za0 = pZ[0], za1 = pZ[1], za2 = pZ[2];
    float wb0 = pW[STRIDE], wb1 = pW[STRIDE+1], wb2 = pW[STRIDE+2];
    float zb0 = pZ[STRIDE], zb1_ = pZ[STRIDE+1], zb2_ = pZ[STRIDE+2];
    pW += 2*STRIDE;  pZ += 2*STRIDE;

    auto step = [&](float nw0, float nw1, float nw2,
                    float nz0, float nz1, float nz2) {
        // h1 frags, both MLPs (B operand: B[k=32f+8q4+j][path=ln15])
        float hhz[16], hhq[16];
#pragma unroll
        for (int idx = 0; idx < 16; ++idx) {
            hhz[idx] = fmaxf(fmaf(B1z[idx], y, fmaf(A1z[idx], t, C1z[idx])), 0.0f);
            hhq[idx] = fmaxf(fmaf(B1q[idx], y, fmaf(A1q[idx], t, C1q[idx])), 0.0f);
        }
        union { unsigned u[4]; bf16x8 v; } bz0v, bz1v, bq0v, bq1v;
#pragma unroll
        for (int m = 0; m < 4; ++m) {
            bz0v.u[m] = packbf16(hhz[2*m],     hhz[2*m + 1]);
            bz1v.u[m] = packbf16(hhz[8 + 2*m], hhz[8 + 2*m + 1]);
            bq0v.u[m] = packbf16(hhq[2*m],     hhq[2*m + 1]);
            bq1v.u[m] = packbf16(hhq[8 + 2*m], hhq[8 + 2*m + 1]);
        }

        // layer-2: Dt[n][path] per MLP; relu -> f16 B-frags for layer-3
        f16x4 B3z[4], B3q[4];
#pragma unroll
        for (int tN = 0; tN < 4; ++tN) {
            f32x4 dz = b2zv[tN];
            dz = __builtin_amdgcn_mfma_f32_16x16x32_bf16(AfZ[tN][0], bz0v.v, dz, 0, 0, 0);
            dz = __builtin_amdgcn_mfma_f32_16x16x32_bf16(AfZ[tN][1], bz1v.v, dz, 0, 0, 0);
            f32x4 dq = b2qv[tN];
            dq = __builtin_amdgcn_mfma_f32_16x16x32_bf16(AfQ[tN][0], bq0v.v, dq, 0, 0, 0);
            dq = __builtin_amdgcn_mfma_f32_16x16x32_bf16(AfQ[tN][1], bq1v.v, dq, 0, 0, 0);
            B3z[tN] = (f16x4){(_Float16)fmaxf(dz[0],0.f), (_Float16)fmaxf(dz[1],0.f),
                              (_Float16)fmaxf(dz[2],0.f), (_Float16)fmaxf(dz[3],0.f)};
            B3q[tN] = (f16x4){(_Float16)fmaxf(dq[0],0.f), (_Float16)fmaxf(dq[1],0.f),
                              (_Float16)fmaxf(dq[2],0.f), (_Float16)fmaxf(dq[3],0.f)};
        }

        // layer-3: stacked P (rows 0-2 = z0..z2, row 3 = q); 2 chains for ILP
        f32x4 Pa = {0,0,0,0}, Pb = {0,0,0,0};
        Pa = __builtin_amdgcn_mfma_f32_16x16x16f16(A3z[0], B3z[0], Pa, 0, 0, 0);
        Pb = __builtin_amdgcn_mfma_f32_16x16x16f16(A3z[1], B3z[1], Pb, 0, 0, 0);
        Pa = __builtin_amdgcn_mfma_f32_16x16x16f16(A3z[2], B3z[2], Pa, 0, 0, 0);
        Pb = __builtin_amdgcn_mfma_f32_16x16x16f16(A3z[3], B3z[3], Pb, 0, 0, 0);
        Pa = __builtin_amdgcn_mfma_f32_16x16x16f16(A3q[0], B3q[0], Pa, 0, 0, 0);
        Pb = __builtin_amdgcn_mfma_f32_16x16x16f16(A3q[1], B3q[1], Pb, 0, 0, 0);
        Pa = __builtin_amdgcn_mfma_f32_16x16x16f16(A3q[2], B3q[2], Pa, 0, 0, 0);
        Pb = __builtin_amdgcn_mfma_f32_16x16x16f16(A3q[3], B3q[3], Pb, 0, 0, 0);
        f32x4 P = Pa + Pb;

        // broadcast this path's outputs from its q4==0 lane
        float z0 = __shfl(P[0], ln15) + zb30;
        float z1 = __shfl(P[1], ln15) + zb31;
        float z2 = __shfl(P[2], ln15) + zb32;
        float qv = __shfl(P[3], ln15) + qb30;

        float dw0 = SQRTDT*nw0, dw1 = SQRTDT*nw1, dw2 = SQRTDT*nw2;
        float e0  = SQRTDT*nz0, e1  = SQRTDT*nz1, e2  = SQRTDT*nz2;
        float zdw = fmaf(z2, dw2, fmaf(z1, dw1, z0*dw0));
        float zdz = fmaf(z2, e2,  fmaf(z1, e1,  z0*e0));
        float f = 0.5f*qv*qv;
        Yv = Yv - f*DT_ + zdw;
        float r = zdw - zdz;                 // residual: (Y - f*DT) cancels
        acc = fmaf(r, r, acc);
        y = y + qv*DT_ + SIGMA0_*(dw0 + dw1 + dw2);
        t += DT_;
    };

#pragma unroll 1
    for (int i = 0; i < NSTEPS; i += 2) {
        step(wa0, wa1, wa2, za0, za1, za2);
        if (i + 2 < NSTEPS) {
            wa0 = pW[0]; wa1 = pW[1]; wa2 = pW[2];
            za0 = pZ[0]; za1 = pZ[1]; za2 = pZ[2];
            pW += STRIDE; pZ += STRIDE;
        }
        step(wb0, wb1, wb2, zb0, zb1_, zb2_);
        if (i + 3 < NSTEPS) {
            wb0 = pW[0]; wb1 = pW[1]; wb2 = pW[2];
            zb0 = pZ[0]; zb1_ = pZ[1]; zb2_ = pZ[2];
            pW += STRIDE; pZ += STRIDE;
        }
    }

    float dterm = Yv - y*y;
    acc = fmaf(dterm, dterm, acc);

    // acc replicated across q4 groups -> count q4==0 only; one atomic per wave
    float val = (q4 == 0) ? acc : 0.0f;
#pragma unroll
    for (int off = 1; off < 64; off <<= 1) val += __shfl_xor(val, off);
    if (lane == 0) atomicAdd(out, val * (1.0f / BATCH));
}

extern "C" void kernel_launch(void* const* d_in, const int* in_sizes, int n_in,
                              void* d_out, int out_size, void* d_ws, size_t ws_size,
                              hipStream_t stream)
{
    zero_out_kernel<<<1, 64, 0, stream>>>((float*)d_out);
    deepbsde_kernel<<<256, 256, 0, stream>>>(
        (const float*)d_in[0],  (const float*)d_in[1],
        (const float*)d_in[2],  (const float*)d_in[3],
        (const float*)d_in[4],  (const float*)d_in[5],
        (const float*)d_in[6],  (const float*)d_in[7],
        (const float*)d_in[8],  (const float*)d_in[9],
        (const float*)d_in[10], (const float*)d_in[11],
        (const float*)d_in[12], (const float*)d_in[13],
        (const float*)d_in[14], (const float*)d_in[15],
        (float*)d_out);
}